// Round 1
// baseline (285.137 us; speedup 1.0000x reference)
//
#include <hip/hip_runtime.h>

// PEG_Shift: depthwise 3x3 conv (stride 1, pad 1, groups=C), power-of-two weights,
// 16-bit fixed-point activations/bias. x: (32,384,56,56) f32.
//
// v2: persistent blocks (1536 = 6/CU exact residency), double-buffered LDS plane,
// issue-early/write-late staging (T14), halo columns (no edge branches),
// row stride 60 dwords (bank-quad spread, 16B-aligned), 1 barrier/plane.

#define DW_C   384
#define DW_H   56
#define DW_W   56
#define DW_HW  3136
#define DW_HW4 784
#define DW_W4  14
#define LDS_STRIDE 60                       // dwords; 60%32=28 -> bank-quad spread, 240B keeps 16B align
#define LDS_SIZE (DW_H * LDS_STRIDE + 4)    // 3364 dwords (right halo of row 55 = dword 3360)
#define PPB 8                               // planes per block; 12288/1536

__device__ __forceinline__ float qfix(float v) {
    // floor(v * 2^16) * 2^-16, clipped to [-2^15, 2^15-1] — exact in fp32
    v = floorf(v * 65536.0f) * (1.0f / 65536.0f);
    return fminf(fmaxf(v, -32768.0f), 32767.0f);
}

__device__ __forceinline__ float4 qfix4(float4 v) {
    v.x = qfix(v.x); v.y = qfix(v.y); v.z = qfix(v.z); v.w = qfix(v.w);
    return v;
}

__global__ __launch_bounds__(256, 6) void peg_shift_dwconv(
    const float* __restrict__ x, const float* __restrict__ wgt,
    const float* __restrict__ bias, float* __restrict__ out)
{
    __shared__ float s[2][LDS_SIZE];

    const int tid = threadIdx.x;
    const int p0  = blockIdx.x * PPB;

    // Per-thread linear float4 indices -> (row, LDS dword offset). Same mapping is
    // used for staging writes and compute reads; reused across all 8 planes.
    int h[4], o[4];
#pragma unroll
    for (int j = 0; j < 4; ++j) {
        int iv = tid + j * 256;
        if (iv > DW_HW4 - 1) iv = DW_HW4 - 1;   // j=3 only used when tid<16
        int hh = iv / DW_W4;
        int w4 = iv - hh * DW_W4;
        h[j] = hh;
        o[j] = hh * LDS_STRIDE + 4 + w4 * 4;    // data dwords 4..59; halos at 3 and 60
    }

    // Zero halo columns of both buffers once (data writes never touch them).
    if (tid < DW_H) {
        s[0][tid * LDS_STRIDE + 3]  = 0.0f;
        s[0][tid * LDS_STRIDE + 60] = 0.0f;
        s[1][tid * LDS_STRIDE + 3]  = 0.0f;
        s[1][tid * LDS_STRIDE + 60] = 0.0f;
    }

    // ---- prologue: stage plane p0 into buffer 0 ----
    {
        const float4* xp4 = (const float4*)(x + (size_t)p0 * DW_HW);
        float4 r0 = xp4[tid], r1 = xp4[tid + 256], r2 = xp4[tid + 512], r3;
        if (tid < 16) r3 = xp4[tid + 768];
        *(float4*)(&s[0][o[0]]) = qfix4(r0);
        *(float4*)(&s[0][o[1]]) = qfix4(r1);
        *(float4*)(&s[0][o[2]]) = qfix4(r2);
        if (tid < 16) *(float4*)(&s[0][o[3]]) = qfix4(r3);
    }
    __syncthreads();

    float* cur = s[0];
    float* nxt = s[1];

#pragma unroll
    for (int k = 0; k < PPB; ++k) {
        const bool more = (k + 1 < PPB);

        // ---- issue next plane's global loads EARLY (consumed after compute) ----
        float4 r0, r1, r2, r3;
        if (more) {
            const float4* np4 = (const float4*)(x + (size_t)(p0 + k + 1) * DW_HW);
            r0 = np4[tid]; r1 = np4[tid + 256]; r2 = np4[tid + 512];
            if (tid < 16) r3 = np4[tid + 768];
        }

        // ---- quantize the 9 weights (power of two) + bias for plane p0+k ----
        const int c = (p0 + k) % DW_C;
        const float* wp = wgt + c * 9;
        float wq[9];
#pragma unroll
        for (int t = 0; t < 9; ++t) {
            float wv = wp[t];
            float aw = fabsf(wv);
            float cw = fminf(fmaxf(aw, 6.103515625e-05f /*2^-14*/), 1.0f);
            float q  = exp2f(rintf(log2f(cw)));    // rint = round-half-even, matches jnp.round
            wq[t] = (wv > 0.0f) ? q : ((wv < 0.0f) ? -q : 0.0f);
        }
        const float bq = qfix(bias[c]);

        float4* op4 = (float4*)(out + (size_t)(p0 + k) * DW_HW);

        // ---- compute plane p0+k from cur ----
#define ROWFMA(RP, W0, W1, W2) {                                      \
            const float* rp_ = (RP);                                  \
            float4 m_ = *(const float4*)rp_;                          \
            float L_ = rp_[-1], R_ = rp_[4];                          \
            a0 = fmaf(L_,   W0, fmaf(m_.x, W1, fmaf(m_.y, W2, a0))); \
            a1 = fmaf(m_.x, W0, fmaf(m_.y, W1, fmaf(m_.z, W2, a1))); \
            a2 = fmaf(m_.y, W0, fmaf(m_.z, W1, fmaf(m_.w, W2, a2))); \
            a3 = fmaf(m_.z, W0, fmaf(m_.w, W1, fmaf(R_,   W2, a3))); }

#define COMPUTE(J) {                                                  \
            float a0 = bq, a1 = bq, a2 = bq, a3 = bq;                 \
            const float* base = cur + o[J];                           \
            if (h[J] > 0)        ROWFMA(base - LDS_STRIDE, wq[0], wq[1], wq[2]); \
            ROWFMA(base, wq[3], wq[4], wq[5]);                        \
            if (h[J] < DW_H - 1) ROWFMA(base + LDS_STRIDE, wq[6], wq[7], wq[8]); \
            float4 ov_; ov_.x = a0; ov_.y = a1; ov_.z = a2; ov_.w = a3; \
            op4[tid + (J) * 256] = ov_; }

        COMPUTE(0)
        COMPUTE(1)
        COMPUTE(2)
        if (tid < 16) COMPUTE(3)

#undef COMPUTE
#undef ROWFMA

        // ---- write next plane to the other buffer (loads drained by now) ----
        if (more) {
            *(float4*)(&nxt[o[0]]) = qfix4(r0);
            *(float4*)(&nxt[o[1]]) = qfix4(r1);
            *(float4*)(&nxt[o[2]]) = qfix4(r2);
            if (tid < 16) *(float4*)(&nxt[o[3]]) = qfix4(r3);
        }
        __syncthreads();
        float* t_ = cur; cur = nxt; nxt = t_;
    }
}

extern "C" void kernel_launch(void* const* d_in, const int* in_sizes, int n_in,
                              void* d_out, int out_size, void* d_ws, size_t ws_size,
                              hipStream_t stream) {
    const float* x = (const float*)d_in[0];
    const float* w = (const float*)d_in[1];
    const float* b = (const float*)d_in[2];
    float* out = (float*)d_out;

    int planes = in_sizes[0] / DW_HW;   // 32 * 384 = 12288
    int nblocks = planes / PPB;         // 1536 = 6 blocks/CU exact residency
    peg_shift_dwconv<<<nblocks, 256, 0, stream>>>(x, w, b, out);
}